// Round 1
// baseline (326.161 us; speedup 1.0000x reference)
//
#include <hip/hip_runtime.h>
#include <climits>

// Problem constants (setup_inputs: B=8, N=20000, G=300, C=80)
#define BB 8
#define NA 20000
#define GG 300
#define NCLS 80
#define KK 4
#define MAXPOS 128
#define T_HIGH 0.7f

// Single compiled instance (noinline) so k1's gt_max and k2's recomputed IoU
// are bitwise identical -> the `iou == gt_max` low-quality match is exact.
__device__ __attribute__((noinline)) float iou_cxcywh(
    float acx, float acy, float aw, float ah,
    float bcx, float bcy, float bw, float bh)
{
    float ax0 = acx - 0.5f * aw, ay0 = acy - 0.5f * ah;
    float ax1 = acx + 0.5f * aw, ay1 = acy + 0.5f * ah;
    float bx0 = bcx - 0.5f * bw, by0 = bcy - 0.5f * bh;
    float bx1 = bcx + 0.5f * bw, by1 = bcy + 0.5f * bh;
    float area_a = (ax1 - ax0) * (ay1 - ay0);
    float area_b = (bx1 - bx0) * (by1 - by0);
    float ltx = fmaxf(ax0, bx0), lty = fmaxf(ay0, by0);
    float rbx = fminf(ax1, bx1), rby = fminf(ay1, by1);
    float wx = fmaxf(rbx - ltx, 0.0f), wy = fmaxf(rby - lty, 0.0f);
    float inter = wx * wy;
    return inter / (area_a + area_b - inter);
}

// ---------------------------------------------------------------------------
// k1: one block per (b,g). Top-4 of the class-masked IoU row + row max.
// Tie-break: higher value first; equal values -> lower anchor index first
// (matches lax.top_k).
// ---------------------------------------------------------------------------
__global__ __launch_bounds__(256) void k1_topk(
    const float* __restrict__ anchors,   // [B,NA,4] cxcywh
    const int*   __restrict__ prompt,    // [B,NA]
    const int*   __restrict__ tlabels,   // [B,G]
    const float* __restrict__ tboxes,    // [B,G,4] cxcywh
    float* __restrict__ gt_max,          // [B,G]
    float* __restrict__ topv,            // [B,G,K]
    int*   __restrict__ topi)            // [B,G,K]
{
    int bg = blockIdx.x;
    int b = bg / GG;
    int lbl = tlabels[bg];
    float4 tb = ((const float4*)tboxes)[bg];
    int tid = threadIdx.x;

    float tv[4] = {-2.0f, -2.0f, -2.0f, -2.0f};   // sentinel < -1 < any IoU
    int   ti[4] = {INT_MAX, INT_MAX, INT_MAX, INT_MAX};

    const int*    prow = prompt + (size_t)b * NA;
    const float4* arow = ((const float4*)anchors) + (size_t)b * NA;

    for (int n = tid; n < NA; n += 256) {
        if (prow[n] == lbl) {
            float4 ab = arow[n];
            float iou = iou_cxcywh(tb.x, tb.y, tb.z, tb.w, ab.x, ab.y, ab.z, ab.w);
            // candidates arrive in increasing n per thread, so equal-value
            // later candidates must NOT displace earlier ones:
            if (iou > tv[3] || (iou == tv[3] && n < ti[3])) {
                tv[3] = iou; ti[3] = n;
#pragma unroll
                for (int j = 3; j > 0; --j) {
                    bool up = (tv[j] > tv[j-1]) || (tv[j] == tv[j-1] && ti[j] < ti[j-1]);
                    if (up) {
                        float fv = tv[j]; tv[j] = tv[j-1]; tv[j-1] = fv;
                        int   ii = ti[j]; ti[j] = ti[j-1]; ti[j-1] = ii;
                    }
                }
            }
        }
    }

    __shared__ float sv[256 * 4];
    __shared__ int   si[256 * 4];
#pragma unroll
    for (int j = 0; j < 4; ++j) { sv[tid*4+j] = tv[j]; si[tid*4+j] = ti[j]; }
    __syncthreads();

    for (int s = 128; s > 0; s >>= 1) {
        if (tid < s) {
            float av[4], bv[4], ov[4];
            int   ai[4], bi[4], oi[4];
#pragma unroll
            for (int j = 0; j < 4; ++j) {
                av[j] = sv[tid*4+j];       ai[j] = si[tid*4+j];
                bv[j] = sv[(tid+s)*4+j];   bi[j] = si[(tid+s)*4+j];
            }
            int x = 0, y = 0;
#pragma unroll
            for (int k = 0; k < 4; ++k) {
                bool takeA = (av[x] > bv[y]) || (av[x] == bv[y] && ai[x] < bi[y]);
                if (takeA) { ov[k] = av[x]; oi[k] = ai[x]; ++x; }
                else       { ov[k] = bv[y]; oi[k] = bi[y]; ++y; }
            }
#pragma unroll
            for (int j = 0; j < 4; ++j) { sv[tid*4+j] = ov[j]; si[tid*4+j] = oi[j]; }
        }
        __syncthreads();
    }

    if (tid == 0) {
        gt_max[bg] = sv[0];   // -2 sentinel behaves like reference -1 (both < 0)
#pragma unroll
        for (int j = 0; j < 4; ++j) { topv[bg*KK+j] = sv[j]; topi[bg*KK+j] = si[j]; }
    }
}

// ---------------------------------------------------------------------------
// k2: one thread per (b,n). anchor_max / first-max argmax / positive flag.
// ---------------------------------------------------------------------------
__global__ __launch_bounds__(256) void k2_anchor(
    const float* __restrict__ anchors,
    const int*   __restrict__ prompt,
    const int*   __restrict__ tlabels,
    const float* __restrict__ tboxes,
    const float* __restrict__ gt_max,
    int* __restrict__ anchor_gt,   // [B,NA]
    int* __restrict__ posf)        // [B,NA]
{
    int b = blockIdx.y;
    int n = blockIdx.x * 256 + threadIdx.x;

    __shared__ float sgb[GG * 4];
    __shared__ int   slbl[GG];
    __shared__ float sgm[GG];
    for (int i = threadIdx.x; i < GG; i += 256) {
        slbl[i] = tlabels[b * GG + i];
        sgm[i]  = gt_max[b * GG + i];
        float4 t = ((const float4*)tboxes)[b * GG + i];
        sgb[i*4+0] = t.x; sgb[i*4+1] = t.y; sgb[i*4+2] = t.z; sgb[i*4+3] = t.w;
    }
    __syncthreads();
    if (n >= NA) return;

    int cls = prompt[(size_t)b * NA + n];
    float4 ab = ((const float4*)anchors)[(size_t)b * NA + n];

    float maxv = -1.0f;   // masked entries are -1; init -1 + strict > keeps
    int   argg = 0;       // first-occurrence argmax semantics (jnp.argmax)
    bool  lq = false;
    for (int g = 0; g < GG; ++g) {
        if (slbl[g] == cls) {
            float iou = iou_cxcywh(sgb[g*4], sgb[g*4+1], sgb[g*4+2], sgb[g*4+3],
                                   ab.x, ab.y, ab.z, ab.w);
            float gm = sgm[g];
            lq = lq || (iou == gm && gm >= 0.0f);
            if (iou > maxv) { maxv = iou; argg = g; }
        }
    }
    bool pos = (maxv >= T_HIGH) || lq;
    anchor_gt[(size_t)b * NA + n] = argg;
    posf[(size_t)b * NA + n] = pos ? 1 : 0;
}

// ---------------------------------------------------------------------------
// k3: one block per (b,class). Ordered rank-within-class < MAXPOS, then
// counts[anchor_gt] += 1 for kept positives. Reproduces the stable
// argsort-by-(class, idx) subsample exactly.
// ---------------------------------------------------------------------------
__global__ __launch_bounds__(256) void k3_subsample(
    const int* __restrict__ prompt,
    const int* __restrict__ posf,
    const int* __restrict__ anchor_gt,
    int* __restrict__ counts)   // [B,G], pre-zeroed
{
    int bc = blockIdx.x;
    int b = bc / NCLS, c = bc % NCLS;
    int tid = threadIdx.x;
    __shared__ int sd[256];

    int running = 0;
    for (int base = 0; base < NA && running < MAXPOS; base += 256) {
        int n = base + tid;
        int flag = 0;
        if (n < NA)
            flag = (posf[(size_t)b*NA + n] && prompt[(size_t)b*NA + n] == c) ? 1 : 0;
        sd[tid] = flag;
        __syncthreads();
        // inclusive Hillis-Steele scan over 256
        for (int off = 1; off < 256; off <<= 1) {
            int v = (tid >= off) ? sd[tid - off] : 0;
            __syncthreads();
            sd[tid] += v;
            __syncthreads();
        }
        int incl  = sd[tid];
        int total = sd[255];
        int rank  = running + incl - flag;   // exclusive rank within class
        if (flag && rank < MAXPOS) {
            atomicAdd(&counts[b * GG + anchor_gt[(size_t)b*NA + n]], 1);
        }
        running += total;
        __syncthreads();
    }
}

// ---------------------------------------------------------------------------
// k4: epilogue. Outputs concatenated [B,G,K] x4 as float32.
// ---------------------------------------------------------------------------
__global__ __launch_bounds__(256) void k4_out(
    const int*   __restrict__ counts,
    const float* __restrict__ topv,
    const int*   __restrict__ topi,
    float* __restrict__ out)
{
    const int TOT = BB * GG * KK;
    int t = blockIdx.x * 256 + threadIdx.x;
    if (t >= TOT) return;
    int k  = t % KK;
    int bg = t / KK;
    int g  = bg % GG;
    int cnt = counts[bg];
    int m = cnt < KK ? cnt : KK;
    bool sv = (k < m);
    out[t]           = sv ? (float)topi[t] : -1.0f;   // pr_inds
    out[TOT + t]     = sv ? (float)g       : -1.0f;   // gt_inds
    out[2*TOT + t]   = sv ? 1.0f : 0.0f;              // slot_valid
    out[3*TOT + t]   = sv ? topv[t] : 0.0f;           // pos_iou
}

extern "C" void kernel_launch(void* const* d_in, const int* in_sizes, int n_in,
                              void* d_out, int out_size, void* d_ws, size_t ws_size,
                              hipStream_t stream) {
    // inputs: 0 pred_logits_match (unused), 1 pred_boxes (unused),
    //         2 anchors, 3 prompt_inds, 4 tgt_labels, 5 tgt_boxes
    const float* anchors = (const float*)d_in[2];
    const int*   prompt  = (const int*)d_in[3];
    const int*   tlabels = (const int*)d_in[4];
    const float* tboxes  = (const float*)d_in[5];
    float* out = (float*)d_out;

    char* ws = (char*)d_ws;
    float* gt_max    = (float*)ws; ws += (size_t)BB*GG*sizeof(float);
    float* topv      = (float*)ws; ws += (size_t)BB*GG*KK*sizeof(float);
    int*   topi      = (int*)ws;   ws += (size_t)BB*GG*KK*sizeof(int);
    int*   anchor_gt = (int*)ws;   ws += (size_t)BB*NA*sizeof(int);
    int*   posf      = (int*)ws;   ws += (size_t)BB*NA*sizeof(int);
    int*   counts    = (int*)ws;   ws += (size_t)BB*GG*sizeof(int);

    hipMemsetAsync(counts, 0, (size_t)BB*GG*sizeof(int), stream);

    k1_topk<<<BB*GG, 256, 0, stream>>>(anchors, prompt, tlabels, tboxes,
                                       gt_max, topv, topi);
    k2_anchor<<<dim3((NA + 255)/256, BB), 256, 0, stream>>>(
        anchors, prompt, tlabels, tboxes, gt_max, anchor_gt, posf);
    k3_subsample<<<BB*NCLS, 256, 0, stream>>>(prompt, posf, anchor_gt, counts);
    k4_out<<<(BB*GG*KK + 255)/256, 256, 0, stream>>>(counts, topv, topi, out);
}

// Round 2
// 168.375 us; speedup vs baseline: 1.9371x; 1.9371x over previous
//
#include <hip/hip_runtime.h>
#include <climits>

// Problem constants (setup_inputs: B=8, N=20000, G=300, C=80)
#define BB 8
#define NA 20000
#define GG 300
#define NCLS 80
#define KK 4
#define MAXPOS 128
#define T_HIGH 0.7f

// Single compiled instance (noinline) so every IoU evaluation in the pipeline
// is bitwise identical (matched numpy exactly in R1: absmax 0.0).
__device__ __attribute__((noinline)) float iou_cxcywh(
    float acx, float acy, float aw, float ah,
    float bcx, float bcy, float bw, float bh)
{
    float ax0 = acx - 0.5f * aw, ay0 = acy - 0.5f * ah;
    float ax1 = acx + 0.5f * aw, ay1 = acy + 0.5f * ah;
    float bx0 = bcx - 0.5f * bw, by0 = bcy - 0.5f * bh;
    float bx1 = bcx + 0.5f * bw, by1 = bcy + 0.5f * bh;
    float area_a = (ax1 - ax0) * (ay1 - ay0);
    float area_b = (bx1 - bx0) * (by1 - by0);
    float ltx = fmaxf(ax0, bx0), lty = fmaxf(ay0, by0);
    float rbx = fminf(ax1, bx1), rby = fminf(ay1, by1);
    float wx = fmaxf(rbx - ltx, 0.0f), wy = fmaxf(rby - lty, 0.0f);
    float inter = wx * wy;
    return inter / (area_a + area_b - inter);
}

// ---------------------------------------------------------------------------
// kab: per-image class histogram + exclusive prefix.
// aoffset has NCLS+1 entries per image (last = NA). cursor = copy for scatter.
// ---------------------------------------------------------------------------
__global__ __launch_bounds__(256) void kab_hist(
    const int* __restrict__ prompt, int* __restrict__ aoffset,
    int* __restrict__ cursor)
{
    int b = blockIdx.x;
    int tid = threadIdx.x;
    __shared__ int cnt[NCLS];
    if (tid < NCLS) cnt[tid] = 0;
    __syncthreads();
    const int* prow = prompt + (size_t)b * NA;
    for (int n = tid; n < NA; n += 256) atomicAdd(&cnt[prow[n]], 1);
    __syncthreads();
    if (tid == 0) {
        int run = 0;
        for (int c = 0; c < NCLS; ++c) {
            aoffset[b * (NCLS + 1) + c] = run;
            cursor[b * NCLS + c] = run;
            run += cnt[c];
        }
        aoffset[b * (NCLS + 1) + NCLS] = run;   // == NA
    }
}

// ---------------------------------------------------------------------------
// kc: scatter anchor indices into per-class buckets (UNORDERED within class —
// safe: all consumers are order-independent (lex top-k, atomicMax)).
// ---------------------------------------------------------------------------
__global__ __launch_bounds__(256) void kc_scatter(
    const int* __restrict__ prompt, int* __restrict__ cursor,
    int* __restrict__ alist)
{
    int b = blockIdx.y;
    int n = blockIdx.x * 256 + threadIdx.x;
    if (n >= NA) return;
    int c = prompt[(size_t)b * NA + n];
    int slot = atomicAdd(&cursor[b * NCLS + c], 1);
    alist[(size_t)b * NA + slot] = n;
}

// ---------------------------------------------------------------------------
// kd: one block per (b,g). Iterates ONLY the gt's class bucket (~N/C anchors).
//  pass 1: lex top-4 (value desc, anchor idx asc == lax.top_k) + per-anchor
//          argmax via packed u64 atomicMax: (iou_bits<<32)|(0x7fffffff-g)
//          -> max iou, ties to smallest g (jnp.argmax first-occurrence).
//  pass 2: low-quality flags: iou == row max (exact, same compiled IoU).
// ---------------------------------------------------------------------------
__global__ __launch_bounds__(256) void kd_main(
    const float* __restrict__ anchors,
    const int*   __restrict__ alist,
    const int*   __restrict__ aoffset,
    const int*   __restrict__ tlabels,
    const float* __restrict__ tboxes,
    unsigned long long* __restrict__ packed,   // [B,NA], pre-zeroed
    int*   __restrict__ posf,                  // [B,NA], pre-zeroed (lq stage)
    float* __restrict__ topv,                  // [B,G,K]
    int*   __restrict__ topi)                  // [B,G,K]
{
    int bg = blockIdx.x;
    int b = bg / GG;
    int g = bg - b * GG;
    int lbl = tlabels[bg];
    float4 tb = ((const float4*)tboxes)[bg];
    int aoff = aoffset[b * (NCLS + 1) + lbl];
    int aend = aoffset[b * (NCLS + 1) + lbl + 1];
    int tid = threadIdx.x;

    const int*    lrow = alist + (size_t)b * NA;
    const float4* arow = ((const float4*)anchors) + (size_t)b * NA;

    float tv[4] = {-2.0f, -2.0f, -2.0f, -2.0f};   // sentinel < any IoU
    int   ti_[4] = {INT_MAX, INT_MAX, INT_MAX, INT_MAX};
    unsigned long long glow = (unsigned long long)(unsigned)(0x7FFFFFFF - g);

    for (int i = aoff + tid; i < aend; i += 256) {
        int n = lrow[i];
        float4 ab = arow[n];
        float iou = iou_cxcywh(tb.x, tb.y, tb.z, tb.w, ab.x, ab.y, ab.z, ab.w);
        // order-independent lex top-4 insert
        if (iou > tv[3] || (iou == tv[3] && n < ti_[3])) {
            tv[3] = iou; ti_[3] = n;
#pragma unroll
            for (int j = 3; j > 0; --j) {
                bool up = (tv[j] > tv[j-1]) || (tv[j] == tv[j-1] && ti_[j] < ti_[j-1]);
                if (up) {
                    float fv = tv[j]; tv[j] = tv[j-1]; tv[j-1] = fv;
                    int   ii = ti_[j]; ti_[j] = ti_[j-1]; ti_[j-1] = ii;
                }
            }
        }
        unsigned long long key = ((unsigned long long)__float_as_uint(iou) << 32) | glow;
        atomicMax(&packed[(size_t)b * NA + n], key);
    }

    __shared__ float sv[256 * 4];
    __shared__ int   si[256 * 4];
#pragma unroll
    for (int j = 0; j < 4; ++j) { sv[tid*4+j] = tv[j]; si[tid*4+j] = ti_[j]; }
    __syncthreads();

    for (int s = 128; s > 0; s >>= 1) {
        if (tid < s) {
            float av[4], bv[4], ov[4];
            int   ai[4], bi[4], oi[4];
#pragma unroll
            for (int j = 0; j < 4; ++j) {
                av[j] = sv[tid*4+j];       ai[j] = si[tid*4+j];
                bv[j] = sv[(tid+s)*4+j];   bi[j] = si[(tid+s)*4+j];
            }
            int x = 0, y = 0;
#pragma unroll
            for (int k = 0; k < 4; ++k) {
                bool takeA = (av[x] > bv[y]) || (av[x] == bv[y] && ai[x] < bi[y]);
                if (takeA) { ov[k] = av[x]; oi[k] = ai[x]; ++x; }
                else       { ov[k] = bv[y]; oi[k] = bi[y]; ++y; }
            }
#pragma unroll
            for (int j = 0; j < 4; ++j) { sv[tid*4+j] = ov[j]; si[tid*4+j] = oi[j]; }
        }
        __syncthreads();
    }

    float sv0 = sv[0];   // gt row max (>=0 iff bucket non-empty)
    for (int i = aoff + tid; i < aend; i += 256) {
        int n = lrow[i];
        float4 ab = arow[n];
        float iou = iou_cxcywh(tb.x, tb.y, tb.z, tb.w, ab.x, ab.y, ab.z, ab.w);
        if (iou == sv0) posf[(size_t)b * NA + n] = 1;   // all writers store 1
    }

    if (tid == 0) {
#pragma unroll
        for (int j = 0; j < 4; ++j) { topv[bg*KK+j] = sv[j]; topi[bg*KK+j] = si[j]; }
    }
}

// ---------------------------------------------------------------------------
// ke: per anchor: unpack argmax, combine pos = lq || max>=0.7, accumulate
// per-class positive totals.
// ---------------------------------------------------------------------------
__global__ __launch_bounds__(256) void ke_pos(
    const int* __restrict__ prompt,
    const unsigned long long* __restrict__ packed,
    int* __restrict__ posf,        // in: lq flag, out: full pos flag
    int* __restrict__ anchor_gt,   // [B,NA]
    int* __restrict__ totals)      // [B,NCLS], pre-zeroed
{
    int b = blockIdx.y;
    int n = blockIdx.x * 256 + threadIdx.x;
    if (n >= NA) return;
    size_t idx = (size_t)b * NA + n;
    unsigned long long p = packed[idx];
    float maxv = __uint_as_float((unsigned)(p >> 32));        // 0.0 if no valid gt
    int argg = p ? (0x7FFFFFFF - (int)(unsigned)(p & 0xFFFFFFFFull)) : 0;
    bool pos = (posf[idx] != 0) || (maxv >= T_HIGH);
    anchor_gt[idx] = argg;
    posf[idx] = pos ? 1 : 0;
    if (pos) atomicAdd(&totals[b * NCLS + prompt[idx]], 1);
}

// ---------------------------------------------------------------------------
// kf: fast path — classes with <= MAXPOS positives keep ALL positives
// (rank is irrelevant), one atomicAdd per positive anchor.
// ---------------------------------------------------------------------------
__global__ __launch_bounds__(256) void kf_fast(
    const int* __restrict__ prompt,
    const int* __restrict__ posf,
    const int* __restrict__ anchor_gt,
    const int* __restrict__ totals,
    int* __restrict__ counts)      // [B,G], pre-zeroed
{
    int b = blockIdx.y;
    int n = blockIdx.x * 256 + threadIdx.x;
    if (n >= NA) return;
    size_t idx = (size_t)b * NA + n;
    if (posf[idx] && totals[b * NCLS + prompt[idx]] <= MAXPOS)
        atomicAdd(&counts[b * GG + anchor_gt[idx]], 1);
}

// ---------------------------------------------------------------------------
// kg: exact fallback for classes with > MAXPOS positives (ordered rank<128,
// stable by anchor index — reproduces the argsort subsample). Early-exits
// immediately for all other (b,c); with this data every block exits.
// ---------------------------------------------------------------------------
__global__ __launch_bounds__(256) void kg_slow(
    const int* __restrict__ prompt,
    const int* __restrict__ posf,
    const int* __restrict__ anchor_gt,
    const int* __restrict__ totals,
    int* __restrict__ counts)
{
    int bc = blockIdx.x;
    int b = bc / NCLS, c = bc % NCLS;
    if (totals[b * NCLS + c] <= MAXPOS) return;
    int tid = threadIdx.x;
    __shared__ int sd[256];

    int running = 0;
    for (int base = 0; base < NA && running < MAXPOS; base += 256) {
        int n = base + tid;
        int flag = 0;
        if (n < NA)
            flag = (posf[(size_t)b*NA + n] && prompt[(size_t)b*NA + n] == c) ? 1 : 0;
        sd[tid] = flag;
        __syncthreads();
        for (int off = 1; off < 256; off <<= 1) {
            int v = (tid >= off) ? sd[tid - off] : 0;
            __syncthreads();
            sd[tid] += v;
            __syncthreads();
        }
        int incl  = sd[tid];
        int total = sd[255];
        int rank  = running + incl - flag;
        if (flag && rank < MAXPOS)
            atomicAdd(&counts[b * GG + anchor_gt[(size_t)b*NA + n]], 1);
        running += total;
        __syncthreads();
    }
}

// ---------------------------------------------------------------------------
// kh: epilogue. Outputs concatenated [B,G,K] x4 as float32.
// ---------------------------------------------------------------------------
__global__ __launch_bounds__(256) void kh_out(
    const int*   __restrict__ counts,
    const float* __restrict__ topv,
    const int*   __restrict__ topi,
    float* __restrict__ out)
{
    const int TOT = BB * GG * KK;
    int t = blockIdx.x * 256 + threadIdx.x;
    if (t >= TOT) return;
    int k  = t % KK;
    int bg = t / KK;
    int g  = bg % GG;
    int cnt = counts[bg];
    int m = cnt < KK ? cnt : KK;
    bool svld = (k < m);
    out[t]           = svld ? (float)topi[t] : -1.0f;   // pr_inds
    out[TOT + t]     = svld ? (float)g       : -1.0f;   // gt_inds
    out[2*TOT + t]   = svld ? 1.0f : 0.0f;              // slot_valid
    out[3*TOT + t]   = svld ? topv[t] : 0.0f;           // pos_iou
}

extern "C" void kernel_launch(void* const* d_in, const int* in_sizes, int n_in,
                              void* d_out, int out_size, void* d_ws, size_t ws_size,
                              hipStream_t stream) {
    // inputs: 0 pred_logits_match (unused), 1 pred_boxes (unused),
    //         2 anchors, 3 prompt_inds, 4 tgt_labels, 5 tgt_boxes
    const float* anchors = (const float*)d_in[2];
    const int*   prompt  = (const int*)d_in[3];
    const int*   tlabels = (const int*)d_in[4];
    const float* tboxes  = (const float*)d_in[5];
    float* out = (float*)d_out;

    char* ws = (char*)d_ws;
    // --- zero-initialized region (contiguous, one memset) ---
    unsigned long long* packed = (unsigned long long*)ws; ws += (size_t)BB*NA*sizeof(unsigned long long);
    int* posf   = (int*)ws; ws += (size_t)BB*NA*sizeof(int);
    int* totals = (int*)ws; ws += (size_t)BB*NCLS*sizeof(int);
    int* counts = (int*)ws; ws += (size_t)BB*GG*sizeof(int);
    size_t zero_bytes = (size_t)(ws - (char*)d_ws);
    // --- scratch written before read ---
    int* aoffset   = (int*)ws; ws += (size_t)BB*(NCLS+1)*sizeof(int);
    int* cursor    = (int*)ws; ws += (size_t)BB*NCLS*sizeof(int);
    int* alist     = (int*)ws; ws += (size_t)BB*NA*sizeof(int);
    int* anchor_gt = (int*)ws; ws += (size_t)BB*NA*sizeof(int);
    float* topv    = (float*)ws; ws += (size_t)BB*GG*KK*sizeof(float);
    int* topi      = (int*)ws; ws += (size_t)BB*GG*KK*sizeof(int);

    hipMemsetAsync(d_ws, 0, zero_bytes, stream);

    dim3 anchorGrid((NA + 255) / 256, BB);
    kab_hist   <<<BB, 256, 0, stream>>>(prompt, aoffset, cursor);
    kc_scatter <<<anchorGrid, 256, 0, stream>>>(prompt, cursor, alist);
    kd_main    <<<BB * GG, 256, 0, stream>>>(anchors, alist, aoffset, tlabels,
                                             tboxes, packed, posf, topv, topi);
    ke_pos     <<<anchorGrid, 256, 0, stream>>>(prompt, packed, posf, anchor_gt, totals);
    kf_fast    <<<anchorGrid, 256, 0, stream>>>(prompt, posf, anchor_gt, totals, counts);
    kg_slow    <<<BB * NCLS, 256, 0, stream>>>(prompt, posf, anchor_gt, totals, counts);
    kh_out     <<<(BB*GG*KK + 255) / 256, 256, 0, stream>>>(counts, topv, topi, out);
}

// Round 3
// 149.630 us; speedup vs baseline: 2.1798x; 1.1253x over previous
//
#include <hip/hip_runtime.h>
#include <climits>

// Problem constants (setup_inputs: B=8, N=20000, G=300, C=80)
#define BB 8
#define NA 20000
#define GG 300
#define NCLS 80
#define KK 4
#define MAXPOS 128
#define T_HIGH 0.7f

// Single compiled instance (noinline) so every IoU evaluation in the pipeline
// is bitwise identical (absmax 0.0 in R1/R2).
__device__ __attribute__((noinline)) float iou_cxcywh(
    float acx, float acy, float aw, float ah,
    float bcx, float bcy, float bw, float bh)
{
    float ax0 = acx - 0.5f * aw, ay0 = acy - 0.5f * ah;
    float ax1 = acx + 0.5f * aw, ay1 = acy + 0.5f * ah;
    float bx0 = bcx - 0.5f * bw, by0 = bcy - 0.5f * bh;
    float bx1 = bcx + 0.5f * bw, by1 = bcy + 0.5f * bh;
    float area_a = (ax1 - ax0) * (ay1 - ay0);
    float area_b = (bx1 - bx0) * (by1 - by0);
    float ltx = fmaxf(ax0, bx0), lty = fmaxf(ay0, by0);
    float rbx = fminf(ax1, bx1), rby = fminf(ay1, by1);
    float wx = fmaxf(rbx - ltx, 0.0f), wy = fmaxf(rby - lty, 0.0f);
    float inter = wx * wy;
    return inter / (area_a + area_b - inter);
}

// merge two sorted-desc top-4 lists (value desc, index asc) -> top-4 of union
__device__ __forceinline__ void merge4(
    const float* av, const int* ai, const float* bv, const int* bi,
    float* ov, int* oi)
{
    int x = 0, y = 0;
#pragma unroll
    for (int k = 0; k < 4; ++k) {
        bool takeA = (av[x] > bv[y]) || (av[x] == bv[y] && ai[x] < bi[y]);
        if (takeA) { ov[k] = av[x]; oi[k] = ai[x]; ++x; }
        else       { ov[k] = bv[y]; oi[k] = bi[y]; ++y; }
    }
}

// ---------------------------------------------------------------------------
// k1_prep: one block per image. Zero-inits scratch, builds the per-image
// class CSR (histogram -> prefix -> scatter) entirely intra-block.
// Bucket order within a class is arbitrary — all consumers are
// order-independent (lex top-k, packed atomicMax, unordered counting).
// ---------------------------------------------------------------------------
__global__ __launch_bounds__(1024) void k1_prep(
    const int* __restrict__ prompt,
    int* __restrict__ aoffset,                  // [B, NCLS+1]
    int* __restrict__ alist,                    // [B, NA]
    unsigned long long* __restrict__ packed,    // [B, NA]  (zeroed here)
    int* __restrict__ posf,                     // [B, NA]  (zeroed here)
    int* __restrict__ totals,                   // [B, NCLS] (zeroed here)
    int* __restrict__ counts)                   // [B, GG]   (zeroed here)
{
    int b = blockIdx.x;
    int tid = threadIdx.x;
    __shared__ int hist[NCLS];
    __shared__ int cur[NCLS];

    // zero-init this image's slices
    for (int n = tid; n < NA; n += 1024) {
        packed[(size_t)b * NA + n] = 0ull;
        posf[(size_t)b * NA + n] = 0;
    }
    if (tid < NCLS) { totals[b * NCLS + tid] = 0; hist[tid] = 0; }
    for (int g = tid; g < GG; g += 1024) counts[b * GG + g] = 0;
    __syncthreads();

    const int* prow = prompt + (size_t)b * NA;
    for (int n = tid; n < NA; n += 1024) atomicAdd(&hist[prow[n]], 1);
    __syncthreads();

    if (tid == 0) {
        int run = 0;
        for (int c = 0; c < NCLS; ++c) {
            aoffset[b * (NCLS + 1) + c] = run;
            cur[c] = run;
            run += hist[c];
        }
        aoffset[b * (NCLS + 1) + NCLS] = run;   // == NA
    }
    __syncthreads();

    for (int n = tid; n < NA; n += 1024) {
        int c = prow[n];
        int slot = atomicAdd(&cur[c], 1);
        alist[(size_t)b * NA + slot] = n;
    }
}

// ---------------------------------------------------------------------------
// k2_gt: one block per (b,g). Iterates ONLY the gt's class bucket.
//  - lex top-4 (value desc, anchor idx asc == lax.top_k), wave shuffle-merge
//  - per-anchor argmax via packed u64 atomicMax (iou_bits<<32 | 0x7fffffff-g)
//  - low-quality flags from register-cached (n, iou) pairs (no re-gather;
//    exact recompute fallback for buckets > 1024)
// ---------------------------------------------------------------------------
__global__ __launch_bounds__(256) void k2_gt(
    const float* __restrict__ anchors,
    const int*   __restrict__ alist,
    const int*   __restrict__ aoffset,
    const int*   __restrict__ tlabels,
    const float* __restrict__ tboxes,
    unsigned long long* __restrict__ packed,
    int*   __restrict__ posf,
    float* __restrict__ topv,    // [B,G,K]
    int*   __restrict__ topi)    // [B,G,K]
{
    int bg = blockIdx.x;
    int b = bg / GG;
    int g = bg - b * GG;
    int lbl = tlabels[bg];
    float4 tb = ((const float4*)tboxes)[bg];
    int aoff = aoffset[b * (NCLS + 1) + lbl];
    int aend = aoffset[b * (NCLS + 1) + lbl + 1];
    int tid = threadIdx.x;

    const int*    lrow = alist + (size_t)b * NA;
    const float4* arow = ((const float4*)anchors) + (size_t)b * NA;

    float tv[4] = {-2.0f, -2.0f, -2.0f, -2.0f};   // sentinel < any IoU
    int   ti_[4] = {INT_MAX, INT_MAX, INT_MAX, INT_MAX};
    float siou[4];
    int   sn[4];
    int   scnt = 0;
    unsigned long long glow = (unsigned long long)(unsigned)(0x7FFFFFFF - g);

    for (int i = aoff + tid; i < aend; i += 256) {
        int n = lrow[i];
        float4 ab = arow[n];
        float iou = iou_cxcywh(tb.x, tb.y, tb.z, tb.w, ab.x, ab.y, ab.z, ab.w);
        if (scnt < 4) { siou[scnt] = iou; sn[scnt] = n; ++scnt; }
        if (iou > tv[3] || (iou == tv[3] && n < ti_[3])) {
            tv[3] = iou; ti_[3] = n;
#pragma unroll
            for (int j = 3; j > 0; --j) {
                bool up = (tv[j] > tv[j-1]) || (tv[j] == tv[j-1] && ti_[j] < ti_[j-1]);
                if (up) {
                    float fv = tv[j]; tv[j] = tv[j-1]; tv[j-1] = fv;
                    int   ii = ti_[j]; ti_[j] = ti_[j-1]; ti_[j-1] = ii;
                }
            }
        }
        unsigned long long key = ((unsigned long long)__float_as_uint(iou) << 32) | glow;
        atomicMax(&packed[(size_t)b * NA + n], key);
    }

    // wave-level butterfly merge (no barriers): 6 rounds, all lanes converge
#pragma unroll
    for (int mask = 1; mask < 64; mask <<= 1) {
        float bv[4], ov[4];
        int   bi[4], oi[4];
#pragma unroll
        for (int j = 0; j < 4; ++j) {
            bv[j] = __shfl_xor(tv[j], mask, 64);
            bi[j] = __shfl_xor(ti_[j], mask, 64);
        }
        merge4(tv, ti_, bv, bi, ov, oi);
#pragma unroll
        for (int j = 0; j < 4; ++j) { tv[j] = ov[j]; ti_[j] = oi[j]; }
    }

    // 4 wave leaders -> LDS, thread 0 does a 4-way merge
    __shared__ float swv[4 * 4];
    __shared__ int   swi[4 * 4];
    __shared__ float smv[4];
    __shared__ int   smi[4];
    int lane = tid & 63, wave = tid >> 6;
    if (lane == 0) {
#pragma unroll
        for (int j = 0; j < 4; ++j) { swv[wave*4+j] = tv[j]; swi[wave*4+j] = ti_[j]; }
    }
    __syncthreads();
    if (tid == 0) {
        int ptr[4] = {0, 0, 0, 0};
#pragma unroll
        for (int k = 0; k < 4; ++k) {
            float bv = -3.0f; int bi = INT_MAX, best = 0;
#pragma unroll
            for (int w = 0; w < 4; ++w) {
                if (ptr[w] < 4) {
                    float v = swv[w*4+ptr[w]]; int ii = swi[w*4+ptr[w]];
                    if (v > bv || (v == bv && ii < bi)) { bv = v; bi = ii; best = w; }
                }
            }
            ++ptr[best];
            smv[k] = bv; smi[k] = bi;
            topv[bg*KK+k] = bv; topi[bg*KK+k] = bi;
        }
    }
    __syncthreads();

    // low-quality: iou == gt row max (exact: same compiled IoU, cached pairs)
    float sv0 = smv[0];
#pragma unroll
    for (int j = 0; j < 4; ++j)
        if (j < scnt && siou[j] == sv0) posf[(size_t)b * NA + sn[j]] = 1;
    // exact fallback for buckets > 4*256 (never taken with this data)
    for (int i = aoff + tid + 1024; i < aend; i += 256) {
        int n = lrow[i];
        float4 ab = arow[n];
        float iou = iou_cxcywh(tb.x, tb.y, tb.z, tb.w, ab.x, ab.y, ab.z, ab.w);
        if (iou == sv0) posf[(size_t)b * NA + n] = 1;
    }
}

// ---------------------------------------------------------------------------
// k3_pos: per anchor: unpack argmax, pos = lq || max>=0.7, class totals.
// ---------------------------------------------------------------------------
__global__ __launch_bounds__(256) void k3_pos(
    const int* __restrict__ prompt,
    const unsigned long long* __restrict__ packed,
    int* __restrict__ posf,        // in: lq flag, out: full pos flag
    int* __restrict__ anchor_gt,   // [B,NA]
    int* __restrict__ totals)      // [B,NCLS]
{
    int idx = blockIdx.x * 256 + threadIdx.x;
    if (idx >= BB * NA) return;
    int b = idx / NA;
    unsigned long long p = packed[idx];
    float maxv = __uint_as_float((unsigned)(p >> 32));        // 0.0 if no valid gt
    int argg = p ? (0x7FFFFFFF - (int)(unsigned)(p & 0xFFFFFFFFull)) : 0;
    bool pos = (posf[idx] != 0) || (maxv >= T_HIGH);
    anchor_gt[idx] = argg;
    posf[idx] = pos ? 1 : 0;
    if (pos) atomicAdd(&totals[b * NCLS + prompt[idx]], 1);
}

// ---------------------------------------------------------------------------
// k4_count: one block per (b,class). Fast path (totals<=MAXPOS: keep ALL
// positives, rank irrelevant) iterates only the class bucket. Exact ordered
// fallback for >MAXPOS (stable rank<128 by anchor index).
// ---------------------------------------------------------------------------
__global__ __launch_bounds__(256) void k4_count(
    const int* __restrict__ prompt,
    const int* __restrict__ alist,
    const int* __restrict__ aoffset,
    const int* __restrict__ posf,
    const int* __restrict__ anchor_gt,
    const int* __restrict__ totals,
    int* __restrict__ counts)      // [B,G]
{
    int bc = blockIdx.x;
    int b = bc / NCLS, c = bc - b * NCLS;
    int tot = totals[b * NCLS + c];
    if (tot == 0) return;
    int tid = threadIdx.x;

    if (tot <= MAXPOS) {
        int aoff = aoffset[b * (NCLS + 1) + c];
        int aend = aoffset[b * (NCLS + 1) + c + 1];
        for (int i = aoff + tid; i < aend; i += 256) {
            int n = alist[(size_t)b * NA + i];
            if (posf[(size_t)b * NA + n])
                atomicAdd(&counts[b * GG + anchor_gt[(size_t)b * NA + n]], 1);
        }
        return;
    }

    // ordered fallback: stable argsort-by-(class, idx) rank < MAXPOS
    __shared__ int sd[256];
    int running = 0;
    for (int base = 0; base < NA && running < MAXPOS; base += 256) {
        int n = base + tid;
        int flag = 0;
        if (n < NA)
            flag = (posf[(size_t)b*NA + n] && prompt[(size_t)b*NA + n] == c) ? 1 : 0;
        sd[tid] = flag;
        __syncthreads();
        for (int off = 1; off < 256; off <<= 1) {
            int v = (tid >= off) ? sd[tid - off] : 0;
            __syncthreads();
            sd[tid] += v;
            __syncthreads();
        }
        int incl  = sd[tid];
        int total = sd[255];
        int rank  = running + incl - flag;
        if (flag && rank < MAXPOS)
            atomicAdd(&counts[b * GG + anchor_gt[(size_t)b*NA + n]], 1);
        running += total;
        __syncthreads();
    }
}

// ---------------------------------------------------------------------------
// k5_out: epilogue. Outputs concatenated [B,G,K] x4 as float32.
// ---------------------------------------------------------------------------
__global__ __launch_bounds__(256) void k5_out(
    const int*   __restrict__ counts,
    const float* __restrict__ topv,
    const int*   __restrict__ topi,
    float* __restrict__ out)
{
    const int TOT = BB * GG * KK;
    int t = blockIdx.x * 256 + threadIdx.x;
    if (t >= TOT) return;
    int k  = t % KK;
    int bg = t / KK;
    int g  = bg % GG;
    int cnt = counts[bg];
    int m = cnt < KK ? cnt : KK;
    bool svld = (k < m);
    out[t]           = svld ? (float)topi[t] : -1.0f;   // pr_inds
    out[TOT + t]     = svld ? (float)g       : -1.0f;   // gt_inds
    out[2*TOT + t]   = svld ? 1.0f : 0.0f;              // slot_valid
    out[3*TOT + t]   = svld ? topv[t] : 0.0f;           // pos_iou
}

extern "C" void kernel_launch(void* const* d_in, const int* in_sizes, int n_in,
                              void* d_out, int out_size, void* d_ws, size_t ws_size,
                              hipStream_t stream) {
    // inputs: 0 pred_logits_match (unused), 1 pred_boxes (unused),
    //         2 anchors, 3 prompt_inds, 4 tgt_labels, 5 tgt_boxes
    const float* anchors = (const float*)d_in[2];
    const int*   prompt  = (const int*)d_in[3];
    const int*   tlabels = (const int*)d_in[4];
    const float* tboxes  = (const float*)d_in[5];
    float* out = (float*)d_out;

    char* ws = (char*)d_ws;
    unsigned long long* packed = (unsigned long long*)ws; ws += (size_t)BB*NA*sizeof(unsigned long long);
    int* posf      = (int*)ws; ws += (size_t)BB*NA*sizeof(int);
    int* totals    = (int*)ws; ws += (size_t)BB*NCLS*sizeof(int);
    int* counts    = (int*)ws; ws += (size_t)BB*GG*sizeof(int);
    int* aoffset   = (int*)ws; ws += (size_t)BB*(NCLS+1)*sizeof(int);
    int* alist     = (int*)ws; ws += (size_t)BB*NA*sizeof(int);
    int* anchor_gt = (int*)ws; ws += (size_t)BB*NA*sizeof(int);
    float* topv    = (float*)ws; ws += (size_t)BB*GG*KK*sizeof(float);
    int* topi      = (int*)ws; ws += (size_t)BB*GG*KK*sizeof(int);

    k1_prep  <<<BB, 1024, 0, stream>>>(prompt, aoffset, alist, packed, posf,
                                       totals, counts);
    k2_gt    <<<BB * GG, 256, 0, stream>>>(anchors, alist, aoffset, tlabels,
                                           tboxes, packed, posf, topv, topi);
    k3_pos   <<<(BB*NA + 255) / 256, 256, 0, stream>>>(prompt, packed, posf,
                                                       anchor_gt, totals);
    k4_count <<<BB * NCLS, 256, 0, stream>>>(prompt, alist, aoffset, posf,
                                             anchor_gt, totals, counts);
    k5_out   <<<(BB*GG*KK + 255) / 256, 256, 0, stream>>>(counts, topv, topi, out);
}

// Round 4
// 120.075 us; speedup vs baseline: 2.7163x; 1.2461x over previous
//
#include <hip/hip_runtime.h>
#include <climits>

// Problem constants (setup_inputs: B=8, N=20000, G=300, C=80)
#define BB 8
#define NA 20000
#define GG 300
#define NCLS 80
#define KK 4
#define MAXPOS 128
#define T_HIGH 0.7f
#define ACACHE 512          // LDS anchor-cache capacity (buckets avg ~250)
#define NBW ((NA + 31) / 32)

// Single compiled instance (noinline) so every IoU evaluation is bitwise
// identical (absmax 0.0 in R1-R3) -> `iou == gt_max` lq test is exact.
__device__ __attribute__((noinline)) float iou_cxcywh(
    float acx, float acy, float aw, float ah,
    float bcx, float bcy, float bw, float bh)
{
    float ax0 = acx - 0.5f * aw, ay0 = acy - 0.5f * ah;
    float ax1 = acx + 0.5f * aw, ay1 = acy + 0.5f * ah;
    float bx0 = bcx - 0.5f * bw, by0 = bcy - 0.5f * bh;
    float bx1 = bcx + 0.5f * bw, by1 = bcy + 0.5f * bh;
    float area_a = (ax1 - ax0) * (ay1 - ay0);
    float area_b = (bx1 - bx0) * (by1 - by0);
    float ltx = fmaxf(ax0, bx0), lty = fmaxf(ay0, by0);
    float rbx = fminf(ax1, bx1), rby = fminf(ay1, by1);
    float wx = fmaxf(rbx - ltx, 0.0f), wy = fmaxf(rby - lty, 0.0f);
    float inter = wx * wy;
    return inter / (area_a + area_b - inter);
}

// merge two sorted-desc top-4 lists (value desc, index asc) -> top-4 of union
__device__ __forceinline__ void merge4(
    const float* av, const int* ai, const float* bv, const int* bi,
    float* ov, int* oi)
{
    int x = 0, y = 0;
#pragma unroll
    for (int k = 0; k < 4; ++k) {
        bool takeA = (av[x] > bv[y]) || (av[x] == bv[y] && ai[x] < bi[y]);
        if (takeA) { ov[k] = av[x]; oi[k] = ai[x]; ++x; }
        else       { ov[k] = bv[y]; oi[k] = bi[y]; ++y; }
    }
}

// ---------------------------------------------------------------------------
// k_main: ONE block per (b, class). Anchors of class c interact only with
// gts of class c, so everything (top-k, argmax, lq, subsample, outputs) is
// intra-block. No global atomics, no workspace, single dispatch.
// ---------------------------------------------------------------------------
__global__ __launch_bounds__(256) void k_main(
    const float* __restrict__ anchors,   // [B,NA,4] cxcywh
    const int*   __restrict__ prompt,    // [B,NA]
    const int*   __restrict__ tlabels,   // [B,G]
    const float* __restrict__ tboxes,    // [B,G,4] cxcywh
    float* __restrict__ out)             // [4][B,G,K] concatenated
{
    int bc = blockIdx.x;
    int b = bc / NCLS, c = bc - b * NCLS;
    int tid = threadIdx.x;
    int lane = tid & 63, wave = tid >> 6;

    __shared__ float4 gbox[GG];              // class gt boxes (ordered by g)
    __shared__ int    gidx[GG];              // class gt global indices
    __shared__ float  gmaxv[GG];             // per-gt row max
    __shared__ int    lcount[GG];            // per-gt positive counts
    __shared__ float  gtv[GG * KK];          // per-gt top-4 values
    __shared__ int    gti[GG * KK];          // per-gt top-4 anchor indices
    __shared__ float4 s_abox[ACACHE];        // bucket anchor boxes
    __shared__ int    s_aidx[ACACHE];        // bucket anchor global indices
    __shared__ unsigned short s_aarg[ACACHE];// per-anchor local argmax
    __shared__ unsigned int s_posbit[NBW];   // positive bitmask
    __shared__ int    sd[256];               // cold-path scan buffer
    __shared__ int    s_wcnt[4];
    __shared__ int    s_acnt, s_ptotal;

    // ---- 1. stable ballot-compaction of class gts (ascending g) ----
    int G_c = 0;
#pragma unroll
    for (int r = 0; r < (GG + 255) / 256; ++r) {
        int j = r * 256 + tid;
        bool flag = (j < GG) && (tlabels[b * GG + j] == c);
        unsigned long long m = __ballot(flag);
        if (lane == 0) s_wcnt[wave] = __popcll(m);
        __syncthreads();
        int off = G_c;
        for (int w = 0; w < wave; ++w) off += s_wcnt[w];
        off += __popcll(m & ((1ull << lane) - 1));
        if (flag) {
            gidx[off] = j;
            gbox[off] = ((const float4*)tboxes)[b * GG + j];
        }
        G_c += s_wcnt[0] + s_wcnt[1] + s_wcnt[2] + s_wcnt[3];
        __syncthreads();
    }
    if (G_c == 0) return;   // no gts of this class -> no outputs owned

    if (tid == 0) { s_acnt = 0; s_ptotal = 0; }
    for (int i = tid; i < NBW; i += 256) s_posbit[i] = 0u;
    for (int gi = tid; gi < G_c; gi += 256) lcount[gi] = 0;
    __syncthreads();

    // ---- 2. collect class anchors into LDS cache (order irrelevant) ----
    const int4*   prow4 = (const int4*)(prompt + (size_t)b * NA);
    const float4* arow  = (const float4*)anchors + (size_t)b * NA;
    for (int q = tid; q < NA / 4; q += 256) {
        int4 p4 = prow4[q];
        int ps[4] = {p4.x, p4.y, p4.z, p4.w};
#pragma unroll
        for (int u = 0; u < 4; ++u) {
            if (ps[u] == c) {
                int slot = atomicAdd(&s_acnt, 1);
                if (slot < ACACHE) {
                    int j = 4 * q + u;
                    s_aidx[slot] = j;
                    s_abox[slot] = arow[j];
                }
            }
        }
    }
    __syncthreads();
    int A_c = s_acnt;
    bool cached = (A_c <= ACACHE);

    // ---- 3. per-gt lex top-4 (value desc, index asc == lax.top_k);
    //         gts round-robin over waves, butterfly merge (no barriers) ----
    for (int gi = wave; gi < G_c; gi += 4) {
        float4 gb = gbox[gi];
        float tv[4]  = {-2.0f, -2.0f, -2.0f, -2.0f};
        int   ti_[4] = {INT_MAX, INT_MAX, INT_MAX, INT_MAX};
        if (cached) {
            for (int slot = lane; slot < A_c; slot += 64) {
                float4 ab = s_abox[slot];
                int n = s_aidx[slot];
                float iou = iou_cxcywh(gb.x, gb.y, gb.z, gb.w, ab.x, ab.y, ab.z, ab.w);
                if (iou > tv[3] || (iou == tv[3] && n < ti_[3])) {
                    tv[3] = iou; ti_[3] = n;
#pragma unroll
                    for (int j = 3; j > 0; --j) {
                        bool up = (tv[j] > tv[j-1]) || (tv[j] == tv[j-1] && ti_[j] < ti_[j-1]);
                        if (up) {
                            float fv = tv[j]; tv[j] = tv[j-1]; tv[j-1] = fv;
                            int   ii = ti_[j]; ti_[j] = ti_[j-1]; ti_[j-1] = ii;
                        }
                    }
                }
            }
        } else {  // cold: bucket overflowed LDS cache -> rescan globally
            for (int n = lane; n < NA; n += 64) {
                if (prompt[(size_t)b * NA + n] != c) continue;
                float4 ab = arow[n];
                float iou = iou_cxcywh(gb.x, gb.y, gb.z, gb.w, ab.x, ab.y, ab.z, ab.w);
                if (iou > tv[3] || (iou == tv[3] && n < ti_[3])) {
                    tv[3] = iou; ti_[3] = n;
#pragma unroll
                    for (int j = 3; j > 0; --j) {
                        bool up = (tv[j] > tv[j-1]) || (tv[j] == tv[j-1] && ti_[j] < ti_[j-1]);
                        if (up) {
                            float fv = tv[j]; tv[j] = tv[j-1]; tv[j-1] = fv;
                            int   ii = ti_[j]; ti_[j] = ti_[j-1]; ti_[j-1] = ii;
                        }
                    }
                }
            }
        }
#pragma unroll
        for (int mask = 1; mask < 64; mask <<= 1) {
            float bv[4], ov[4];
            int   bi[4], oi[4];
#pragma unroll
            for (int j = 0; j < 4; ++j) {
                bv[j] = __shfl_xor(tv[j], mask, 64);
                bi[j] = __shfl_xor(ti_[j], mask, 64);
            }
            merge4(tv, ti_, bv, bi, ov, oi);
#pragma unroll
            for (int j = 0; j < 4; ++j) { tv[j] = ov[j]; ti_[j] = oi[j]; }
        }
        if (lane == 0) {
            gmaxv[gi] = tv[0];
#pragma unroll
            for (int k = 0; k < 4; ++k) { gtv[gi*KK+k] = tv[k]; gti[gi*KK+k] = ti_[k]; }
        }
    }
    __syncthreads();

    // ---- 4. per-anchor: argmax (first occurrence, gidx ascending + strict >),
    //         lq (iou == gt row max, exact), pos, per-gt counts ----
    if (cached) {
        for (int slot = tid; slot < A_c; slot += 256) {
            float4 ab = s_abox[slot];
            float amax = -1.0f; int aarg = 0; bool lq = false;
            for (int gi = 0; gi < G_c; ++gi) {
                float4 gb = gbox[gi];
                float iou = iou_cxcywh(gb.x, gb.y, gb.z, gb.w, ab.x, ab.y, ab.z, ab.w);
                lq = lq || (iou == gmaxv[gi]);
                if (iou > amax) { amax = iou; aarg = gi; }
            }
            s_aarg[slot] = (unsigned short)aarg;
            if (lq || amax >= T_HIGH) {
                atomicOr(&s_posbit[slot >> 5], 1u << (slot & 31));
                atomicAdd(&lcount[aarg], 1);
                atomicAdd(&s_ptotal, 1);
            }
        }
    } else {  // cold: bitmask indexed by global anchor index
        for (int n = tid; n < NA; n += 256) {
            if (prompt[(size_t)b * NA + n] != c) continue;
            float4 ab = arow[n];
            float amax = -1.0f; int aarg = 0; bool lq = false;
            for (int gi = 0; gi < G_c; ++gi) {
                float4 gb = gbox[gi];
                float iou = iou_cxcywh(gb.x, gb.y, gb.z, gb.w, ab.x, ab.y, ab.z, ab.w);
                lq = lq || (iou == gmaxv[gi]);
                if (iou > amax) { amax = iou; aarg = gi; }
            }
            if (lq || amax >= T_HIGH) {
                atomicOr(&s_posbit[n >> 5], 1u << (n & 31));
                atomicAdd(&lcount[aarg], 1);
                atomicAdd(&s_ptotal, 1);
            }
        }
    }
    __syncthreads();
    int ptotal = s_ptotal;

    // ---- 5. subsample: > MAXPOS positives -> keep first MAXPOS by anchor
    //         index (exact stable argsort-by-(class,idx) rank) ----
    if (ptotal > MAXPOS) {
        for (int gi = tid; gi < G_c; gi += 256) lcount[gi] = 0;
        __syncthreads();
        if (cached) {
            for (int slot = tid; slot < A_c; slot += 256) {
                if (!((s_posbit[slot >> 5] >> (slot & 31)) & 1)) continue;
                int n = s_aidx[slot];
                int rank = 0;
                for (int s2 = 0; s2 < A_c; ++s2)
                    if (((s_posbit[s2 >> 5] >> (s2 & 31)) & 1) && s_aidx[s2] < n) ++rank;
                if (rank < MAXPOS) atomicAdd(&lcount[s_aarg[slot]], 1);
            }
        } else {  // cold^2: ordered block scan over the bitmask
            int running = 0;
            for (int base = 0; base < NA && running < MAXPOS; base += 256) {
                int n = base + tid;
                int flag = (n < NA) && ((s_posbit[n >> 5] >> (n & 31)) & 1);
                sd[tid] = flag;
                __syncthreads();
                for (int off = 1; off < 256; off <<= 1) {
                    int v = (tid >= off) ? sd[tid - off] : 0;
                    __syncthreads();
                    sd[tid] += v;
                    __syncthreads();
                }
                int rank = running + sd[tid] - flag;
                int total = sd[255];
                if (flag && rank < MAXPOS) {
                    float4 ab = arow[n];
                    float amax = -1.0f; int aarg = 0;
                    for (int gi = 0; gi < G_c; ++gi) {
                        float4 gb = gbox[gi];
                        float iou = iou_cxcywh(gb.x, gb.y, gb.z, gb.w, ab.x, ab.y, ab.z, ab.w);
                        if (iou > amax) { amax = iou; aarg = gi; }
                    }
                    atomicAdd(&lcount[aarg], 1);
                }
                running += total;
                __syncthreads();
            }
        }
        __syncthreads();
    }

    // ---- 6. outputs for this class's gts: [4][B,G,K] concatenated ----
    const int TOT = BB * GG * KK;
    for (int t = tid; t < G_c * KK; t += 256) {
        int gi = t >> 2, k = t & 3;
        int gg = gidx[gi];
        int cnt = lcount[gi]; if (cnt > KK) cnt = KK;
        bool svld = (k < cnt);
        int o = (b * GG + gg) * KK + k;
        out[o]           = svld ? (float)gti[t] : -1.0f;   // pr_inds
        out[TOT + o]     = svld ? (float)gg     : -1.0f;   // gt_inds
        out[2*TOT + o]   = svld ? 1.0f : 0.0f;             // slot_valid
        out[3*TOT + o]   = svld ? gtv[t] : 0.0f;           // pos_iou
    }
}

extern "C" void kernel_launch(void* const* d_in, const int* in_sizes, int n_in,
                              void* d_out, int out_size, void* d_ws, size_t ws_size,
                              hipStream_t stream) {
    // inputs: 0 pred_logits_match (unused), 1 pred_boxes (unused),
    //         2 anchors, 3 prompt_inds, 4 tgt_labels, 5 tgt_boxes
    const float* anchors = (const float*)d_in[2];
    const int*   prompt  = (const int*)d_in[3];
    const int*   tlabels = (const int*)d_in[4];
    const float* tboxes  = (const float*)d_in[5];
    float* out = (float*)d_out;

    k_main<<<BB * NCLS, 256, 0, stream>>>(anchors, prompt, tlabels, tboxes, out);
}